// Round 1
// baseline (8621.259 us; speedup 1.0000x reference)
//
#include <hip/hip_runtime.h>
#include <hip/hip_fp16.h>

// Problem constants
#define NL   12
#define DMODEL 256
#define NH   8
#define DKH  32
#define FFD  1024
#define BB   32
#define LL   448
#define MTOK (BB*LL)          // 14336
#define EPSF 1e-6f

// ---------------------------------------------------------------------------
// x = x_in + pos_emb  (broadcast over batch), float4 elementwise
// grid 3584, block 256 : 917504 float4 = 32*448*256/4 exactly
__global__ __launch_bounds__(256) void add_pos_k(
    const float* __restrict__ x, const float* __restrict__ pe,
    float* __restrict__ out)
{
    int i = blockIdx.x * 256 + threadIdx.x;            // float4 index
    float4 xv = ((const float4*)x)[i];
    float4 pv = ((const float4*)pe)[i % (LL * DMODEL / 4)];
    float4 r;
    r.x = xv.x + pv.x; r.y = xv.y + pv.y; r.z = xv.z + pv.z; r.w = xv.w + pv.w;
    ((float4*)out)[i] = r;
}

// ---------------------------------------------------------------------------
// LayerNorm over D=256, one wave (64 lanes) per row, 4 rows/block
__global__ __launch_bounds__(256) void ln_k(
    const float* __restrict__ x, const float* __restrict__ g,
    const float* __restrict__ b, float* __restrict__ out)
{
    const int w = threadIdx.x >> 6, lane = threadIdx.x & 63;
    const int row = blockIdx.x * 4 + w;
    const float4* xr = (const float4*)(x + (size_t)row * DMODEL);
    float4 v = xr[lane];
    float s = v.x + v.y + v.z + v.w;
#pragma unroll
    for (int off = 32; off; off >>= 1) s += __shfl_xor(s, off);
    float mu = s * (1.0f / 256.0f);
    float d0 = v.x - mu, d1 = v.y - mu, d2 = v.z - mu, d3 = v.w - mu;
    float sq = d0*d0 + d1*d1 + d2*d2 + d3*d3;
#pragma unroll
    for (int off = 32; off; off >>= 1) sq += __shfl_xor(sq, off);
    float rs = rsqrtf(sq * (1.0f / 256.0f) + EPSF);
    float4 gv = ((const float4*)g)[lane];
    float4 bv = ((const float4*)b)[lane];
    float4 o;
    o.x = d0 * rs * gv.x + bv.x;
    o.y = d1 * rs * gv.y + bv.y;
    o.z = d2 * rs * gv.z + bv.z;
    o.w = d3 * rs * gv.w + bv.w;
    ((float4*)(out + (size_t)row * DMODEL))[lane] = o;
}

// ---------------------------------------------------------------------------
// fp32 GEMM  C = A[M,K] @ W[K,N] + bias  (row-major), 64x64 tile, BK=16
// EPI: 0 = store, 1 = GELU(exact)+store, 2 = C += (residual read-modify-write)
__device__ __forceinline__ float gelu_exact(float x) {
    return 0.5f * x * (1.0f + erff(x * 0.70710678118654752f));
}

template <int EPI>
__global__ __launch_bounds__(256) void gemm_k(
    const float* __restrict__ A, const float* __restrict__ W,
    const float* __restrict__ bias, float* __restrict__ C,
    int N, int K)
{
    __shared__ float As[16][68];   // [k][m], padded: 68*4B = 17 banks stride
    __shared__ float Ws[16][64];   // [k][n]
    const int tid = threadIdx.x;
    const int bx = blockIdx.x, by = blockIdx.y;
    const int tx = tid & 15, ty = tid >> 4;
    const int ar = tid >> 2, ac4 = tid & 3;   // A loader: row 0..63, colgrp 0..3
    const int wr = tid >> 4, wc = tid & 15;   // W loader: row 0..15, colgrp 0..15

    const float* Ap = A + (size_t)(by * 64 + ar) * K + ac4 * 4;
    const float* Wp = W + (size_t)wr * N + bx * 64 + wc * 4;

    float acc[4][4] = {};

    for (int k0 = 0; k0 < K; k0 += 16) {
        float4 a4 = *(const float4*)Ap;
        float4 w4 = *(const float4*)Wp;
        Ap += 16;
        Wp += (size_t)16 * N;
        As[ac4 * 4 + 0][ar] = a4.x;
        As[ac4 * 4 + 1][ar] = a4.y;
        As[ac4 * 4 + 2][ar] = a4.z;
        As[ac4 * 4 + 3][ar] = a4.w;
        *(float4*)&Ws[wr][wc * 4] = w4;
        __syncthreads();
#pragma unroll
        for (int kk = 0; kk < 16; ++kk) {
            float4 av = *(const float4*)&As[kk][ty * 4];
            float4 wv = *(const float4*)&Ws[kk][tx * 4];
            float am[4] = {av.x, av.y, av.z, av.w};
            float wn[4] = {wv.x, wv.y, wv.z, wv.w};
#pragma unroll
            for (int i = 0; i < 4; ++i)
#pragma unroll
                for (int j = 0; j < 4; ++j) acc[i][j] += am[i] * wn[j];
        }
        __syncthreads();
    }

    const int row0 = by * 64 + ty * 4;
    const int col0 = bx * 64 + tx * 4;
    const float4 bb = *(const float4*)&bias[col0];
#pragma unroll
    for (int i = 0; i < 4; ++i) {
        float r0 = acc[i][0] + bb.x;
        float r1 = acc[i][1] + bb.y;
        float r2 = acc[i][2] + bb.z;
        float r3 = acc[i][3] + bb.w;
        if (EPI == 1) {
            r0 = gelu_exact(r0); r1 = gelu_exact(r1);
            r2 = gelu_exact(r2); r3 = gelu_exact(r3);
        }
        float* cp = C + (size_t)(row0 + i) * N + col0;
        if (EPI == 2) {
            float4 old = *(const float4*)cp;
            r0 += old.x; r1 += old.y; r2 += old.z; r3 += old.w;
        }
        float4 st; st.x = r0; st.y = r1; st.z = r2; st.w = r3;
        *(float4*)cp = st;
    }
}

// ---------------------------------------------------------------------------
// Attention: one block per (b, h, query-half). K,V staged in LDS as fp16.
// Each wave handles one query at a time: lanes own 7 keys each (448 = 7*64),
// softmax via wave shuffles, AV with p broadcast via __shfl (no LDS p).
__global__ __launch_bounds__(256) void attn_k(
    const float* __restrict__ q, const float* __restrict__ k,
    const float* __restrict__ v, const unsigned char* __restrict__ mask,
    float* __restrict__ o)
{
    __shared__ __half Ksh[LL][34];   // row stride 68B -> 17-bank stride, conflict-free
    __shared__ __half Vsh[LL][34];
    const int tid = threadIdx.x;
    const int bh = blockIdx.x >> 1;          // 0..255
    const int qhalf = blockIdx.x & 1;        // queries [0,224) or [224,448)
    const int b = bh >> 3, h = bh & 7;
    const size_t base = ((size_t)b * LL) * DMODEL + h * DKH;

    for (int i = tid; i < LL * 8; i += 256) {
        int row = i >> 3, c4 = i & 7;
        float4 kv = *(const float4*)(k + base + (size_t)row * DMODEL + c4 * 4);
        float4 vv = *(const float4*)(v + base + (size_t)row * DMODEL + c4 * 4);
        __half2* kd = (__half2*)&Ksh[row][c4 * 4];
        kd[0] = __floats2half2_rn(kv.x, kv.y);
        kd[1] = __floats2half2_rn(kv.z, kv.w);
        __half2* vd = (__half2*)&Vsh[row][c4 * 4];
        vd[0] = __floats2half2_rn(vv.x, vv.y);
        vd[1] = __floats2half2_rn(vv.z, vv.w);
    }
    __syncthreads();

    const int w = tid >> 6, lane = tid & 63;
    bool mreg[7];
#pragma unroll
    for (int m = 0; m < 7; ++m) mreg[m] = mask[b * LL + lane + 64 * m] != 0;

    const int d2 = lane & 15, grp = lane >> 4;

    for (int it = 0; it < 56; ++it) {
        const int iq = qhalf * 224 + it * 4 + w;
        const float4* qr = (const float4*)(q + base + (size_t)iq * DMODEL);
        float qreg[32];
#pragma unroll
        for (int c4 = 0; c4 < 8; ++c4) {
            float4 t = qr[c4];
            qreg[c4 * 4 + 0] = t.x; qreg[c4 * 4 + 1] = t.y;
            qreg[c4 * 4 + 2] = t.z; qreg[c4 * 4 + 3] = t.w;
        }
        float s[7];
#pragma unroll
        for (int m = 0; m < 7; ++m) {
            const int j = lane + 64 * m;
            const __half2* kr = (const __half2*)&Ksh[j][0];
            float acc = 0.f;
#pragma unroll
            for (int t = 0; t < 16; ++t) {
                float2 kf = __half22float2(kr[t]);
                acc += qreg[2 * t] * kf.x + qreg[2 * t + 1] * kf.y;
            }
            s[m] = mreg[m] ? -10000.0f : acc * 0.17677669529663687f;
        }
        float mx = s[0];
#pragma unroll
        for (int m = 1; m < 7; ++m) mx = fmaxf(mx, s[m]);
#pragma unroll
        for (int off = 32; off; off >>= 1) mx = fmaxf(mx, __shfl_xor(mx, off));
        float p[7], sum = 0.f;
#pragma unroll
        for (int m = 0; m < 7; ++m) { p[m] = __expf(s[m] - mx); sum += p[m]; }
#pragma unroll
        for (int off = 32; off; off >>= 1) sum += __shfl_xor(sum, off);
        const float inv = 1.0f / sum;

        // AV: lane owns dim-pair d2 for key-group grp; p broadcast via shfl
        float a0 = 0.f, a1 = 0.f;
#pragma unroll
        for (int m = 0; m < 7; ++m) {
#pragma unroll
            for (int jj = 0; jj < 16; ++jj) {
                const int j = 64 * m + 4 * jj + grp;
                float pp = __shfl(p[m], 4 * jj + grp);
                float2 vf = __half22float2(*(const __half2*)&Vsh[j][d2 * 2]);
                a0 += pp * vf.x; a1 += pp * vf.y;
            }
        }
        a0 += __shfl_xor(a0, 16); a1 += __shfl_xor(a1, 16);
        a0 += __shfl_xor(a0, 32); a1 += __shfl_xor(a1, 32);
        if (lane < 16) {
            float2 r; r.x = a0 * inv; r.y = a1 * inv;
            *(float2*)(o + base + (size_t)iq * DMODEL + d2 * 2) = r;
        }
    }
}

// ---------------------------------------------------------------------------
extern "C" void kernel_launch(void* const* d_in, const int* in_sizes, int n_in,
                              void* d_out, int out_size, void* d_ws, size_t ws_size,
                              hipStream_t stream)
{
    const float* x_in = (const float*)d_in[0];
    const unsigned char* mask = (const unsigned char*)d_in[1];
    const float* pe   = (const float*)d_in[2];
    const float* Wq = (const float*)d_in[3];
    const float* bq = (const float*)d_in[4];
    const float* Wk = (const float*)d_in[5];
    const float* bk = (const float*)d_in[6];
    const float* Wv = (const float*)d_in[7];
    const float* bv = (const float*)d_in[8];
    const float* Wo = (const float*)d_in[9];
    const float* bo = (const float*)d_in[10];
    const float* W1 = (const float*)d_in[11];
    const float* bf1 = (const float*)d_in[12];
    const float* W2 = (const float*)d_in[13];
    const float* bf2 = (const float*)d_in[14];
    const float* ln1_g = (const float*)d_in[15];
    const float* ln1_b = (const float*)d_in[16];
    const float* ln2_g = (const float*)d_in[17];
    const float* ln2_b = (const float*)d_in[18];

    float* x = (float*)d_out;                 // running activation [M, D]
    const size_t MD = (size_t)MTOK * DMODEL;  // 3,670,016
    float* nx = (float*)d_ws;                 // [M, D]
    float* qb = nx + MD;
    float* kb = qb + MD;
    float* vb = kb + MD;
    float* ob = vb + MD;
    float* hb = qb;                           // [M, FFD] reuses q|k|v|o region

    add_pos_k<<<MTOK * DMODEL / 1024, 256, 0, stream>>>(x_in, pe, x);

    for (int l = 0; l < NL; ++l) {
        const float* wq = Wq + (size_t)l * DMODEL * DMODEL;
        const float* wk = Wk + (size_t)l * DMODEL * DMODEL;
        const float* wv = Wv + (size_t)l * DMODEL * DMODEL;
        const float* wo = Wo + (size_t)l * DMODEL * DMODEL;
        const float* w1 = W1 + (size_t)l * DMODEL * FFD;
        const float* w2 = W2 + (size_t)l * FFD * DMODEL;

        ln_k<<<MTOK / 4, 256, 0, stream>>>(x, ln1_g + l * DMODEL, ln1_b + l * DMODEL, nx);

        gemm_k<0><<<dim3(DMODEL / 64, MTOK / 64), 256, 0, stream>>>(nx, wq, bq + l * DMODEL, qb, DMODEL, DMODEL);
        gemm_k<0><<<dim3(DMODEL / 64, MTOK / 64), 256, 0, stream>>>(nx, wk, bk + l * DMODEL, kb, DMODEL, DMODEL);
        gemm_k<0><<<dim3(DMODEL / 64, MTOK / 64), 256, 0, stream>>>(nx, wv, bv + l * DMODEL, vb, DMODEL, DMODEL);

        attn_k<<<512, 256, 0, stream>>>(qb, kb, vb, mask, ob);

        gemm_k<2><<<dim3(DMODEL / 64, MTOK / 64), 256, 0, stream>>>(ob, wo, bo + l * DMODEL, x, DMODEL, DMODEL);

        ln_k<<<MTOK / 4, 256, 0, stream>>>(x, ln2_g + l * DMODEL, ln2_b + l * DMODEL, nx);

        gemm_k<1><<<dim3(FFD / 64, MTOK / 64), 256, 0, stream>>>(nx, w1, bf1 + l * FFD, hb, FFD, DMODEL);
        gemm_k<2><<<dim3(DMODEL / 64, MTOK / 64), 256, 0, stream>>>(hb, w2, bf2 + l * DMODEL, x, DMODEL, FFD);
    }
}

// Round 2
// 1750.315 us; speedup vs baseline: 4.9255x; 4.9255x over previous
//
#include <hip/hip_runtime.h>

#define NL 12
#define DM 256
#define FFDIM 1024
#define BBATCH 32
#define LSEQ 448
#define MTOK (BBATCH*LSEQ)     // 14336
#define EPSF 1e-6f

typedef __attribute__((ext_vector_type(8))) short bf16x8;
typedef __attribute__((ext_vector_type(4))) float f32x4;
typedef unsigned short u16;
typedef unsigned int u32;

__device__ __forceinline__ u16 f2bf(float f) {
    union { float f; u32 u; } v; v.f = f;
    u32 r = v.u + 0x7fffu + ((v.u >> 16) & 1u);
    return (u16)(r >> 16);
}
__device__ __forceinline__ float gelu_exact(float x) {
    return 0.5f * x * (1.0f + erff(x * 0.70710678118654752f));
}

// ---------------------------------------------------------------------------
// x = x_in + pos_emb (broadcast over batch), fp32 residual stream
__global__ __launch_bounds__(256) void add_pos_k(
    const float* __restrict__ x, const float* __restrict__ pe, float* __restrict__ out)
{
    int i = blockIdx.x * 256 + threadIdx.x;
    float4 xv = ((const float4*)x)[i];
    float4 pv = ((const float4*)pe)[i % (LSEQ * DM / 4)];
    float4 r;
    r.x = xv.x + pv.x; r.y = xv.y + pv.y; r.z = xv.z + pv.z; r.w = xv.w + pv.w;
    ((float4*)out)[i] = r;
}

// ---------------------------------------------------------------------------
// LayerNorm over D=256, wave per row, 4 rows/block, bf16 output
__global__ __launch_bounds__(256) void ln_k(
    const float* __restrict__ x, const float* __restrict__ g,
    const float* __restrict__ b, u16* __restrict__ out)
{
    const int w = threadIdx.x >> 6, lane = threadIdx.x & 63;
    const int row = blockIdx.x * 4 + w;
    float4 v = ((const float4*)(x + (size_t)row * DM))[lane];
    float s = v.x + v.y + v.z + v.w;
#pragma unroll
    for (int off = 32; off; off >>= 1) s += __shfl_xor(s, off);
    float mu = s * (1.0f / 256.0f);
    float d0 = v.x - mu, d1 = v.y - mu, d2 = v.z - mu, d3 = v.w - mu;
    float sq = d0*d0 + d1*d1 + d2*d2 + d3*d3;
#pragma unroll
    for (int off = 32; off; off >>= 1) sq += __shfl_xor(sq, off);
    float rs = rsqrtf(sq * (1.0f / 256.0f) + EPSF);
    float4 gv = ((const float4*)g)[lane];
    float4 bv = ((const float4*)b)[lane];
    ushort4 o;
    o.x = f2bf(d0 * rs * gv.x + bv.x);
    o.y = f2bf(d1 * rs * gv.y + bv.y);
    o.z = f2bf(d2 * rs * gv.z + bv.z);
    o.w = f2bf(d3 * rs * gv.w + bv.w);
    *(ushort4*)(out + (size_t)row * DM + lane * 4) = o;
}

// ---------------------------------------------------------------------------
// Weight transpose + cvt: in fp32 [layer][K][N] -> out bf16 [layer][N][K]
__global__ __launch_bounds__(256) void twt_k(
    const float* __restrict__ in, u16* __restrict__ out,
    int K, int N, int in_lstride, int out_lstride)
{
    __shared__ float tl[32][33];
    const int l = blockIdx.z;
    const int n0 = blockIdx.x * 32, k0 = blockIdx.y * 32;
    const int tx = threadIdx.x & 31, ty = threadIdx.x >> 5;
    const float* src = in + (size_t)l * in_lstride;
#pragma unroll
    for (int i = 0; i < 4; ++i)
        tl[ty + 8*i][tx] = src[(size_t)(k0 + ty + 8*i) * N + n0 + tx];
    __syncthreads();
    u16* dst = out + (size_t)l * out_lstride;
#pragma unroll
    for (int i = 0; i < 4; ++i)
        dst[(size_t)(n0 + ty + 8*i) * K + k0 + tx] = f2bf(tl[tx][ty + 8*i]);
}

// Pack bq|bk|bv into fused fp32 [12][768]
__global__ __launch_bounds__(256) void pack_bias_k(
    const float* __restrict__ bq, const float* __restrict__ bk,
    const float* __restrict__ bv, float* __restrict__ bqkv)
{
    int i = blockIdx.x * 256 + threadIdx.x;
    if (i >= NL * 768) return;
    int l = i / 768, c = i % 768;
    float v = (c < 256) ? bq[l*256 + c] : (c < 512) ? bk[l*256 + c - 256] : bv[l*256 + c - 512];
    bqkv[i] = v;
}

// ---------------------------------------------------------------------------
// V transpose per layer: qkv cols [512,768) bf16 -> vtg [b][h][d=32][key=448]
__global__ __launch_bounds__(256) void vt_k(
    const u16* __restrict__ qkv, u16* __restrict__ vtg)
{
    __shared__ u16 tl[32][33];
    const int kt = blockIdx.x, h = blockIdx.y, b = blockIdx.z;
    const int tx = threadIdx.x & 31, ty = threadIdx.x >> 5;
#pragma unroll
    for (int i = 0; i < 4; ++i)
        tl[ty + 8*i][tx] = qkv[(size_t)(b*LSEQ + kt*32 + ty + 8*i) * 768 + 512 + h*32 + tx];
    __syncthreads();
#pragma unroll
    for (int i = 0; i < 4; ++i)
        vtg[((size_t)(b*8 + h)*32 + ty + 8*i) * 448 + kt*32 + tx] = tl[tx][ty + 8*i];
}

// ---------------------------------------------------------------------------
// bf16 MFMA GEMM: C = A[M,K] @ Bt[N,K]^T + bias. BM=128, BK=32, BN template.
// EPI: 0 = bf16 store, 1 = gelu->bf16 store, 2 = fp32 residual +=
template<int BN, int EPI>
__global__ __launch_bounds__(256, 2) void mm_k(
    const u16* __restrict__ A, int lda, const u16* __restrict__ Bt,
    const float* __restrict__ bias, void* __restrict__ C, int ldc, int K)
{
    __shared__ u16 As[128 * 32];
    __shared__ u16 Bs[BN * 32];
    constexpr int MT = (BN == 128) ? 4 : 2;
    const int tid = threadIdx.x;
    const int bx = blockIdx.x, by = blockIdx.y;
    const int w = tid >> 6, lane = tid & 63;
    const int lm = lane & 15, lk = lane >> 4;
    const int wm = (BN == 128) ? (w >> 1) : w;
    const int wn = (BN == 128) ? (w & 1) : 0;
    const int m0 = wm * MT * 16;
    const int n0 = wn * 64;
    const int ar = tid >> 2, akg = tid & 3;

    const u16* Ab = A + (size_t)(by * 128) * lda;
    const u16* Bb = Bt + (size_t)(bx * BN) * K;

    f32x4 zz = {0.f, 0.f, 0.f, 0.f};
    f32x4 acc[MT][4];
#pragma unroll
    for (int i = 0; i < MT; ++i)
#pragma unroll
        for (int j = 0; j < 4; ++j) acc[i][j] = zz;

    for (int k0 = 0; k0 < K; k0 += 32) {
        uint4 a0 = *(const uint4*)(Ab + (size_t)ar * lda + k0 + akg*8);
        uint4 a1 = *(const uint4*)(Ab + (size_t)(64 + ar) * lda + k0 + akg*8);
        uint4 b0 = *(const uint4*)(Bb + (size_t)ar * K + k0 + akg*8);
        uint4 b1 = {};
        if constexpr (BN == 128)
            b1 = *(const uint4*)(Bb + (size_t)(64 + ar) * K + k0 + akg*8);
        __syncthreads();
        *(uint4*)&As[ar*32 + akg*8] = a0;
        *(uint4*)&As[(64 + ar)*32 + akg*8] = a1;
        *(uint4*)&Bs[ar*32 + akg*8] = b0;
        if constexpr (BN == 128)
            *(uint4*)&Bs[(64 + ar)*32 + akg*8] = b1;
        __syncthreads();
        bf16x8 af[MT], bfr[4];
#pragma unroll
        for (int mt = 0; mt < MT; ++mt)
            af[mt] = *(const bf16x8*)&As[(m0 + mt*16 + lm)*32 + lk*8];
#pragma unroll
        for (int nt = 0; nt < 4; ++nt)
            bfr[nt] = *(const bf16x8*)&Bs[(n0 + nt*16 + lm)*32 + lk*8];
#pragma unroll
        for (int mt = 0; mt < MT; ++mt)
#pragma unroll
            for (int nt = 0; nt < 4; ++nt)
                acc[mt][nt] = __builtin_amdgcn_mfma_f32_16x16x32_bf16(af[mt], bfr[nt], acc[mt][nt], 0, 0, 0);
    }

    float bv[4];
#pragma unroll
    for (int nt = 0; nt < 4; ++nt) bv[nt] = bias[bx*BN + n0 + nt*16 + lm];
#pragma unroll
    for (int mt = 0; mt < MT; ++mt) {
#pragma unroll
        for (int r = 0; r < 4; ++r) {
            int grow = by*128 + m0 + mt*16 + lk*4 + r;
#pragma unroll
            for (int nt = 0; nt < 4; ++nt) {
                int gcol = bx*BN + n0 + nt*16 + lm;
                float vv = acc[mt][nt][r] + bv[nt];
                if constexpr (EPI == 0) {
                    ((u16*)C)[(size_t)grow * ldc + gcol] = f2bf(vv);
                } else if constexpr (EPI == 1) {
                    ((u16*)C)[(size_t)grow * ldc + gcol] = f2bf(gelu_exact(vv));
                } else {
                    float* p = (float*)C + (size_t)grow * ldc + gcol;
                    *p += vv;
                }
            }
        }
    }
}

// ---------------------------------------------------------------------------
// MFMA attention: block per (b,h,half). K in LDS; V^T from global vtg.
// Each wave: 16-query strip, 28 QK mfma, reg softmax, P->LDS->A-frag, 28 PV mfma.
__global__ __launch_bounds__(256, 2) void attn_k(
    const u16* __restrict__ qkv, const u16* __restrict__ vtg,
    const unsigned char* __restrict__ mask, u16* __restrict__ ob)
{
    __shared__ u16 Klds[448 * 32];
    __shared__ u16 Plds[4][16 * 64];
    const int tid = threadIdx.x, w = tid >> 6, lane = tid & 63;
    const int lm = lane & 15, lk = lane >> 4;
    const int bid = blockIdx.x;
    const int b = bid >> 4, h = (bid >> 1) & 7, half = bid & 1;
    const size_t rowbase = (size_t)b * LSEQ;

    for (int cid = tid; cid < 448 * 4; cid += 256) {
        int row = cid >> 2, kg = cid & 3;
        *(uint4*)&Klds[row*32 + kg*8] =
            *(const uint4*)(qkv + (rowbase + row)*768 + 256 + h*32 + kg*8);
    }
    unsigned mbits = 0;
#pragma unroll
    for (int t = 0; t < 28; ++t)
        mbits |= (mask[b*LSEQ + t*16 + lm] ? 1u : 0u) << t;
    __syncthreads();

    const u16* Vb = vtg + (size_t)(b*8 + h) * 32 * 448;
    const float scale = 0.17677669529663687f;
    f32x4 zz = {0.f, 0.f, 0.f, 0.f};

    for (int s = w; s < 14; s += 4) {
        const int q0 = half * 224 + s * 16;
        bf16x8 qf = *(const bf16x8*)(qkv + (rowbase + q0 + lm)*768 + h*32 + lk*8);
        f32x4 sc[28];
#pragma unroll
        for (int t = 0; t < 28; ++t) {
            bf16x8 kf = *(const bf16x8*)&Klds[(t*16 + lm)*32 + lk*8];
            sc[t] = __builtin_amdgcn_mfma_f32_16x16x32_bf16(qf, kf, zz, 0, 0, 0);
        }
        float mx[4] = {-1e30f, -1e30f, -1e30f, -1e30f};
#pragma unroll
        for (int t = 0; t < 28; ++t) {
            bool m = (mbits >> t) & 1;
#pragma unroll
            for (int r = 0; r < 4; ++r) {
                float v = m ? -10000.0f : sc[t][r] * scale;
                sc[t][r] = v;
                mx[r] = fmaxf(mx[r], v);
            }
        }
#pragma unroll
        for (int off = 1; off < 16; off <<= 1)
#pragma unroll
            for (int r = 0; r < 4; ++r) mx[r] = fmaxf(mx[r], __shfl_xor(mx[r], off));
        float sum[4] = {0.f, 0.f, 0.f, 0.f};
#pragma unroll
        for (int t = 0; t < 28; ++t)
#pragma unroll
            for (int r = 0; r < 4; ++r) {
                float e = __expf(sc[t][r] - mx[r]);
                sc[t][r] = e;
                sum[r] += e;
            }
#pragma unroll
        for (int off = 1; off < 16; off <<= 1)
#pragma unroll
            for (int r = 0; r < 4; ++r) sum[r] += __shfl_xor(sum[r], off);
        float inv[4];
#pragma unroll
        for (int r = 0; r < 4; ++r) inv[r] = 1.0f / sum[r];

        f32x4 oacc[2] = {zz, zz};
        u16* P = &Plds[w][0];
#pragma unroll
        for (int cc = 0; cc < 7; ++cc) {
#pragma unroll
            for (int tt = 0; tt < 4; ++tt) {
                int t = cc*4 + tt;
#pragma unroll
                for (int r = 0; r < 4; ++r)
                    P[(lk*4 + r)*64 + tt*16 + lm] = f2bf(sc[t][r] * inv[r]);
            }
            bf16x8 pa0 = *(const bf16x8*)&P[lm*64 + lk*8];
            bf16x8 pa1 = *(const bf16x8*)&P[lm*64 + 32 + lk*8];
#pragma unroll
            for (int dt = 0; dt < 2; ++dt) {
                bf16x8 vb0 = *(const bf16x8*)(Vb + (size_t)(dt*16 + lm)*448 + cc*64 + lk*8);
                bf16x8 vb1 = *(const bf16x8*)(Vb + (size_t)(dt*16 + lm)*448 + cc*64 + 32 + lk*8);
                oacc[dt] = __builtin_amdgcn_mfma_f32_16x16x32_bf16(pa0, vb0, oacc[dt], 0, 0, 0);
                oacc[dt] = __builtin_amdgcn_mfma_f32_16x16x32_bf16(pa1, vb1, oacc[dt], 0, 0, 0);
            }
        }
#pragma unroll
        for (int dt = 0; dt < 2; ++dt)
#pragma unroll
            for (int r = 0; r < 4; ++r)
                ob[(rowbase + q0 + lk*4 + r)*256 + h*32 + dt*16 + lm] = f2bf(oacc[dt][r]);
    }
}

// ---------------------------------------------------------------------------
extern "C" void kernel_launch(void* const* d_in, const int* in_sizes, int n_in,
                              void* d_out, int out_size, void* d_ws, size_t ws_size,
                              hipStream_t stream)
{
    const float* x_in = (const float*)d_in[0];
    const unsigned char* mask = (const unsigned char*)d_in[1];
    const float* pe   = (const float*)d_in[2];
    const float* Wq = (const float*)d_in[3];
    const float* bq = (const float*)d_in[4];
    const float* Wk = (const float*)d_in[5];
    const float* bk = (const float*)d_in[6];
    const float* Wv = (const float*)d_in[7];
    const float* bv = (const float*)d_in[8];
    const float* Wo = (const float*)d_in[9];
    const float* bo = (const float*)d_in[10];
    const float* W1 = (const float*)d_in[11];
    const float* bf1 = (const float*)d_in[12];
    const float* W2 = (const float*)d_in[13];
    const float* bf2 = (const float*)d_in[14];
    const float* ln1_g = (const float*)d_in[15];
    const float* ln1_b = (const float*)d_in[16];
    const float* ln2_g = (const float*)d_in[17];
    const float* ln2_b = (const float*)d_in[18];

    float* x = (float*)d_out;                 // fp32 residual stream [M,256]
    u16* ws = (u16*)d_ws;
    u16* nx   = ws;                           //  3,670,016 elems [M,256] bf16
    u16* qkv  = nx + 3670016;                 // 11,010,048 elems [M,768] bf16
    u16* ob   = qkv + 11010048;               //  3,670,016 elems [M,256] bf16
    u16* vtg  = ob + 3670016;                 //  3,670,016 elems [b,h,32,448] bf16
    u16* hb   = qkv;                          // alias qkv+ob: [M,1024] bf16
    u16* wqkvt = vtg + 3670016;               //  2,359,296 elems [12][768][256]
    u16* wot  = wqkvt + 2359296;              //    786,432 elems [12][256][256]
    u16* w1t  = wot + 786432;                 //  3,145,728 elems [12][1024][256]
    u16* w2t  = w1t + 3145728;                //  3,145,728 elems [12][256][1024]
    float* bqkv = (float*)(w2t + 3145728);    //      9,216 floats [12][768]

    add_pos_k<<<MTOK * DM / 1024, 256, 0, stream>>>(x_in, pe, x);

    // one-time (per call) weight prepack
    twt_k<<<dim3(8, 8, NL), 256, 0, stream>>>(Wq, wqkvt,          256, 256, 65536, 196608);
    twt_k<<<dim3(8, 8, NL), 256, 0, stream>>>(Wk, wqkvt + 65536,  256, 256, 65536, 196608);
    twt_k<<<dim3(8, 8, NL), 256, 0, stream>>>(Wv, wqkvt + 131072, 256, 256, 65536, 196608);
    twt_k<<<dim3(8, 8, NL), 256, 0, stream>>>(Wo, wot, 256, 256, 65536, 65536);
    twt_k<<<dim3(32, 8, NL), 256, 0, stream>>>(W1, w1t, 256, 1024, 262144, 262144);
    twt_k<<<dim3(8, 32, NL), 256, 0, stream>>>(W2, w2t, 1024, 256, 262144, 262144);
    pack_bias_k<<<(NL * 768 + 255) / 256, 256, 0, stream>>>(bq, bk, bv, bqkv);

    for (int l = 0; l < NL; ++l) {
        ln_k<<<MTOK / 4, 256, 0, stream>>>(x, ln1_g + l*256, ln1_b + l*256, nx);
        mm_k<128, 0><<<dim3(6, 112), 256, 0, stream>>>(
            nx, 256, wqkvt + (size_t)l*196608, bqkv + l*768, qkv, 768, 256);
        vt_k<<<dim3(14, 8, 32), 256, 0, stream>>>(qkv, vtg);
        attn_k<<<512, 256, 0, stream>>>(qkv, vtg, mask, ob);
        mm_k<64, 2><<<dim3(4, 112), 256, 0, stream>>>(
            ob, 256, wot + (size_t)l*65536, bo + l*256, x, 256, 256);
        ln_k<<<MTOK / 4, 256, 0, stream>>>(x, ln2_g + l*256, ln2_b + l*256, nx);
        mm_k<128, 1><<<dim3(8, 112), 256, 0, stream>>>(
            nx, 256, w1t + (size_t)l*262144, bf1 + l*1024, hb, 1024, 256);
        mm_k<64, 2><<<dim3(4, 112), 256, 0, stream>>>(
            hb, 1024, w2t + (size_t)l*262144, bf2 + l*256, x, 256, 1024);
    }
}

// Round 3
// 1710.135 us; speedup vs baseline: 5.0413x; 1.0235x over previous
//
#include <hip/hip_runtime.h>

#define NL 12
#define DM 256
#define FFDIM 1024
#define BBATCH 32
#define LSEQ 448
#define MTOK (BBATCH*LSEQ)     // 14336
#define EPSF 1e-6f

typedef __attribute__((ext_vector_type(8))) short bf16x8;
typedef __attribute__((ext_vector_type(4))) float f32x4;
typedef unsigned short u16;
typedef unsigned int u32;

__device__ __forceinline__ u16 f2bf(float f) {
    union { float f; u32 u; } v; v.f = f;
    u32 r = v.u + 0x7fffu + ((v.u >> 16) & 1u);
    return (u16)(r >> 16);
}
__device__ __forceinline__ float gelu_exact(float x) {
    return 0.5f * x * (1.0f + erff(x * 0.70710678118654752f));
}
// async global->LDS, 16B per lane; lds base must be wave-uniform
__device__ __forceinline__ void gload16(const u16* g, u16* l) {
    __builtin_amdgcn_global_load_lds(
        (const __attribute__((address_space(1))) u32*)g,
        (__attribute__((address_space(3))) u32*)l, 16, 0, 0);
}

// ---------------------------------------------------------------------------
__global__ __launch_bounds__(256) void add_pos_k(
    const float* __restrict__ x, const float* __restrict__ pe, float* __restrict__ out)
{
    int i = blockIdx.x * 256 + threadIdx.x;
    float4 xv = ((const float4*)x)[i];
    float4 pv = ((const float4*)pe)[i % (LSEQ * DM / 4)];
    float4 r;
    r.x = xv.x + pv.x; r.y = xv.y + pv.y; r.z = xv.z + pv.z; r.w = xv.w + pv.w;
    ((float4*)out)[i] = r;
}

// ---------------------------------------------------------------------------
__global__ __launch_bounds__(256) void ln_k(
    const float* __restrict__ x, const float* __restrict__ g,
    const float* __restrict__ b, u16* __restrict__ out)
{
    const int w = threadIdx.x >> 6, lane = threadIdx.x & 63;
    const int row = blockIdx.x * 4 + w;
    float4 v = ((const float4*)(x + (size_t)row * DM))[lane];
    float s = v.x + v.y + v.z + v.w;
#pragma unroll
    for (int off = 32; off; off >>= 1) s += __shfl_xor(s, off);
    float mu = s * (1.0f / 256.0f);
    float d0 = v.x - mu, d1 = v.y - mu, d2 = v.z - mu, d3 = v.w - mu;
    float sq = d0*d0 + d1*d1 + d2*d2 + d3*d3;
#pragma unroll
    for (int off = 32; off; off >>= 1) sq += __shfl_xor(sq, off);
    float rs = rsqrtf(sq * (1.0f / 256.0f) + EPSF);
    float4 gv = ((const float4*)g)[lane];
    float4 bv = ((const float4*)b)[lane];
    ushort4 o;
    o.x = f2bf(d0 * rs * gv.x + bv.x);
    o.y = f2bf(d1 * rs * gv.y + bv.y);
    o.z = f2bf(d2 * rs * gv.z + bv.z);
    o.w = f2bf(d3 * rs * gv.w + bv.w);
    *(ushort4*)(out + (size_t)row * DM + lane * 4) = o;
}

// ---------------------------------------------------------------------------
// Weight transpose + cvt: fp32 [layer][K][N] -> bf16 [layer][N][K]
__global__ __launch_bounds__(256) void twt_k(
    const float* __restrict__ in, u16* __restrict__ out,
    int K, int N, int in_lstride, int out_lstride)
{
    __shared__ float tl[32][33];
    const int l = blockIdx.z;
    const int n0 = blockIdx.x * 32, k0 = blockIdx.y * 32;
    const int tx = threadIdx.x & 31, ty = threadIdx.x >> 5;
    const float* src = in + (size_t)l * in_lstride;
#pragma unroll
    for (int i = 0; i < 4; ++i)
        tl[ty + 8*i][tx] = src[(size_t)(k0 + ty + 8*i) * N + n0 + tx];
    __syncthreads();
    u16* dst = out + (size_t)l * out_lstride;
#pragma unroll
    for (int i = 0; i < 4; ++i)
        dst[(size_t)(n0 + ty + 8*i) * K + k0 + tx] = f2bf(tl[tx][ty + 8*i]);
}

__global__ __launch_bounds__(256) void pack_bias_k(
    const float* __restrict__ bq, const float* __restrict__ bk,
    const float* __restrict__ bv, float* __restrict__ bqkv)
{
    int i = blockIdx.x * 256 + threadIdx.x;
    if (i >= NL * 768) return;
    int l = i / 768, c = i % 768;
    float v = (c < 256) ? bq[l*256 + c] : (c < 512) ? bk[l*256 + c - 256] : bv[l*256 + c - 512];
    bqkv[i] = v;
}

// ---------------------------------------------------------------------------
// V transpose per layer: qkv cols [512,768) -> vtg [b][h][d=32][key=448]
__global__ __launch_bounds__(256) void vt_k(
    const u16* __restrict__ qkv, u16* __restrict__ vtg)
{
    __shared__ u16 tl[32][33];
    const int kt = blockIdx.x, h = blockIdx.y, b = blockIdx.z;
    const int tx = threadIdx.x & 31, ty = threadIdx.x >> 5;
#pragma unroll
    for (int i = 0; i < 4; ++i)
        tl[ty + 8*i][tx] = qkv[(size_t)(b*LSEQ + kt*32 + ty + 8*i) * 768 + 512 + h*32 + tx];
    __syncthreads();
#pragma unroll
    for (int i = 0; i < 4; ++i)
        vtg[((size_t)(b*8 + h)*32 + ty + 8*i) * 448 + kt*32 + tx] = tl[tx][ty + 8*i];
}

// ---------------------------------------------------------------------------
// bf16 MFMA GEMM (m97 structure): C = A[M,K] @ Bt[N,K]^T + bias.
// BM=128, BK=32, BN in {64,128}. Staging via global_load_lds width=16.
// EPI: 0 = bf16 store, 1 = gelu->bf16 store, 2 = fp32 residual +=
template<int BN, int EPI>
__global__ __launch_bounds__(256, 2) void mm_k(
    const u16* __restrict__ A, int lda, const u16* __restrict__ Bt,
    const float* __restrict__ bias, void* __restrict__ C, int ldc, int K)
{
    __shared__ u16 As[128 * 32];
    __shared__ u16 Bs[BN * 32];
    constexpr int MT = (BN == 128) ? 4 : 2;
    const int tid = threadIdx.x;
    const int bx = blockIdx.x, by = blockIdx.y;
    const int w = tid >> 6, lane = tid & 63;
    const int lm = lane & 15, lk = lane >> 4;
    const int wm = (BN == 128) ? (w >> 1) : w;
    const int wn = (BN == 128) ? (w & 1) : 0;
    const int m0 = wm * MT * 16;
    const int n0 = wn * 64;
    const int lrow = lane >> 2, lcol = (lane & 3) * 8;   // staging lane map

    const u16* Ab = A + (size_t)(by * 128) * lda;
    const u16* Bb = Bt + (size_t)(bx * BN) * K;

    f32x4 zz = {0.f, 0.f, 0.f, 0.f};
    f32x4 acc[MT][4];
#pragma unroll
    for (int i = 0; i < MT; ++i)
#pragma unroll
        for (int j = 0; j < 4; ++j) acc[i][j] = zz;

    for (int k0 = 0; k0 < K; k0 += 32) {
        __syncthreads();      // previous iteration's frags consumed
        // A: 8 segs of 16 rows; wave w stages segs 2w, 2w+1
#pragma unroll
        for (int i = 0; i < 2; ++i) {
            int seg = w * 2 + i;
            gload16(Ab + (size_t)(seg * 16 + lrow) * lda + k0 + lcol, &As[seg * 512]);
        }
        // B: BN/16 segs
        if constexpr (BN == 128) {
#pragma unroll
            for (int i = 0; i < 2; ++i) {
                int seg = w * 2 + i;
                gload16(Bb + (size_t)(seg * 16 + lrow) * K + k0 + lcol, &Bs[seg * 512]);
            }
        } else {
            gload16(Bb + (size_t)(w * 16 + lrow) * K + k0 + lcol, &Bs[w * 512]);
        }
        __syncthreads();      // loads landed (barrier drains vmcnt)

        bf16x8 af[MT], bfr[4];
#pragma unroll
        for (int mt = 0; mt < MT; ++mt)
            af[mt] = *(const bf16x8*)&As[(m0 + mt*16 + lm)*32 + lk*8];
#pragma unroll
        for (int nt = 0; nt < 4; ++nt)
            bfr[nt] = *(const bf16x8*)&Bs[(n0 + nt*16 + lm)*32 + lk*8];
#pragma unroll
        for (int mt = 0; mt < MT; ++mt)
#pragma unroll
            for (int nt = 0; nt < 4; ++nt)
                acc[mt][nt] = __builtin_amdgcn_mfma_f32_16x16x32_bf16(af[mt], bfr[nt], acc[mt][nt], 0, 0, 0);
    }

    float bv[4];
#pragma unroll
    for (int nt = 0; nt < 4; ++nt) bv[nt] = bias[bx*BN + n0 + nt*16 + lm];
#pragma unroll
    for (int mt = 0; mt < MT; ++mt) {
#pragma unroll
        for (int r = 0; r < 4; ++r) {
            int grow = by*128 + m0 + mt*16 + lk*4 + r;
#pragma unroll
            for (int nt = 0; nt < 4; ++nt) {
                int gcol = bx*BN + n0 + nt*16 + lm;
                float vv = acc[mt][nt][r] + bv[nt];
                if constexpr (EPI == 0) {
                    ((u16*)C)[(size_t)grow * ldc + gcol] = f2bf(vv);
                } else if constexpr (EPI == 1) {
                    ((u16*)C)[(size_t)grow * ldc + gcol] = f2bf(gelu_exact(vv));
                } else {
                    float* p = (float*)C + (size_t)grow * ldc + gcol;
                    *p += vv;
                }
            }
        }
    }
}

// ---------------------------------------------------------------------------
// MFMA attention. Grid: (b,h)*7 blocks; wave = one 16-query strip (28 strips/bh).
// K staged via global_load_lds (28KB, bank-balanced). P in padded LDS (row=68).
// P left unnormalized into PV; O scaled by 1/sum at the end.
__global__ __launch_bounds__(256, 2) void attn_k(
    const u16* __restrict__ qkv, const u16* __restrict__ vtg,
    const unsigned char* __restrict__ mask, u16* __restrict__ ob)
{
    __shared__ u16 Klds[448 * 32];
    __shared__ u16 Plds[4][16 * 68];
    const int tid = threadIdx.x, w = tid >> 6, lane = tid & 63;
    const int lm = lane & 15, lk = lane >> 4;
    const int bid = blockIdx.x;
    const int bh = bid / 7, sg = bid % 7;
    const int b = bh >> 3, h = bh & 7;
    const size_t rowbase = (size_t)b * LSEQ;

    // stage K[448][32]: 28 segs of 16 rows, 7 per wave
#pragma unroll
    for (int i = 0; i < 7; ++i) {
        int seg = w * 7 + i;
        gload16(qkv + (rowbase + seg * 16 + (lane >> 2)) * 768 + 256 + h * 32 + (lane & 3) * 8,
                &Klds[seg * 512]);
    }
    unsigned mbits = 0;
#pragma unroll
    for (int t = 0; t < 28; ++t)
        mbits |= (mask[b * LSEQ + t * 16 + lm] ? 1u : 0u) << t;
    __syncthreads();

    const u16* Vb = vtg + (size_t)bh * 32 * 448;
    const float scale = 0.17677669529663687f;
    f32x4 zz = {0.f, 0.f, 0.f, 0.f};

    const int q0 = (sg * 4 + w) * 16;
    bf16x8 qf = *(const bf16x8*)(qkv + (rowbase + q0 + lm) * 768 + h * 32 + lk * 8);
    f32x4 sc[28];
#pragma unroll
    for (int t = 0; t < 28; ++t) {
        bf16x8 kf = *(const bf16x8*)&Klds[(t*16 + lm)*32 + lk*8];
        sc[t] = __builtin_amdgcn_mfma_f32_16x16x32_bf16(qf, kf, zz, 0, 0, 0);
    }
    float mx[4] = {-1e30f, -1e30f, -1e30f, -1e30f};
#pragma unroll
    for (int t = 0; t < 28; ++t) {
        bool m = (mbits >> t) & 1;
#pragma unroll
        for (int r = 0; r < 4; ++r) {
            float v = m ? -10000.0f : sc[t][r] * scale;
            sc[t][r] = v;
            mx[r] = fmaxf(mx[r], v);
        }
    }
#pragma unroll
    for (int off = 1; off < 16; off <<= 1)
#pragma unroll
        for (int r = 0; r < 4; ++r) mx[r] = fmaxf(mx[r], __shfl_xor(mx[r], off));
    float sum[4] = {0.f, 0.f, 0.f, 0.f};
#pragma unroll
    for (int t = 0; t < 28; ++t)
#pragma unroll
        for (int r = 0; r < 4; ++r) {
            float e = __expf(sc[t][r] - mx[r]);
            sc[t][r] = e;
            sum[r] += e;
        }
#pragma unroll
    for (int off = 1; off < 16; off <<= 1)
#pragma unroll
        for (int r = 0; r < 4; ++r) sum[r] += __shfl_xor(sum[r], off);
    float inv[4];
#pragma unroll
    for (int r = 0; r < 4; ++r) inv[r] = 1.0f / sum[r];

    f32x4 oacc[2] = {zz, zz};
    u16* P = &Plds[w][0];
#pragma unroll
    for (int cc = 0; cc < 7; ++cc) {
#pragma unroll
        for (int tt = 0; tt < 4; ++tt) {
            int t = cc*4 + tt;
#pragma unroll
            for (int r = 0; r < 4; ++r)
                P[(lk*4 + r)*68 + tt*16 + lm] = f2bf(sc[t][r]);
        }
        bf16x8 pa0 = *(const bf16x8*)&P[lm*68 + lk*8];
        bf16x8 pa1 = *(const bf16x8*)&P[lm*68 + 32 + lk*8];
#pragma unroll
        for (int dt = 0; dt < 2; ++dt) {
            bf16x8 vb0 = *(const bf16x8*)(Vb + (size_t)(dt*16 + lm)*448 + cc*64 + lk*8);
            bf16x8 vb1 = *(const bf16x8*)(Vb + (size_t)(dt*16 + lm)*448 + cc*64 + 32 + lk*8);
            oacc[dt] = __builtin_amdgcn_mfma_f32_16x16x32_bf16(pa0, vb0, oacc[dt], 0, 0, 0);
            oacc[dt] = __builtin_amdgcn_mfma_f32_16x16x32_bf16(pa1, vb1, oacc[dt], 0, 0, 0);
        }
    }
#pragma unroll
    for (int dt = 0; dt < 2; ++dt)
#pragma unroll
        for (int r = 0; r < 4; ++r)
            ob[(rowbase + q0 + lk*4 + r)*256 + h*32 + dt*16 + lm] = f2bf(oacc[dt][r] * inv[r]);
}

// ---------------------------------------------------------------------------
extern "C" void kernel_launch(void* const* d_in, const int* in_sizes, int n_in,
                              void* d_out, int out_size, void* d_ws, size_t ws_size,
                              hipStream_t stream)
{
    const float* x_in = (const float*)d_in[0];
    const unsigned char* mask = (const unsigned char*)d_in[1];
    const float* pe   = (const float*)d_in[2];
    const float* Wq = (const float*)d_in[3];
    const float* bq = (const float*)d_in[4];
    const float* Wk = (const float*)d_in[5];
    const float* bk = (const float*)d_in[6];
    const float* Wv = (const float*)d_in[7];
    const float* bv = (const float*)d_in[8];
    const float* Wo = (const float*)d_in[9];
    const float* bo = (const float*)d_in[10];
    const float* W1 = (const float*)d_in[11];
    const float* bf1 = (const float*)d_in[12];
    const float* W2 = (const float*)d_in[13];
    const float* bf2 = (const float*)d_in[14];
    const float* ln1_g = (const float*)d_in[15];
    const float* ln1_b = (const float*)d_in[16];
    const float* ln2_g = (const float*)d_in[17];
    const float* ln2_b = (const float*)d_in[18];

    float* x = (float*)d_out;                 // fp32 residual stream [M,256]
    u16* ws = (u16*)d_ws;
    u16* nx   = ws;                           //  [M,256] bf16
    u16* qkv  = nx + 3670016;                 //  [M,768] bf16
    u16* ob   = qkv + 11010048;               //  [M,256] bf16
    u16* vtg  = ob + 3670016;                 //  [b,h,32,448] bf16
    u16* hb   = qkv;                          //  [M,1024] bf16 (aliases qkv)
    u16* wqkvt = vtg + 3670016;               //  [12][768][256]
    u16* wot  = wqkvt + 2359296;              //  [12][256][256]
    u16* w1t  = wot + 786432;                 //  [12][1024][256]
    u16* w2t  = w1t + 3145728;                //  [12][256][1024]
    float* bqkv = (float*)(w2t + 3145728);    //  [12][768]

    add_pos_k<<<MTOK * DM / 1024, 256, 0, stream>>>(x_in, pe, x);

    twt_k<<<dim3(8, 8, NL), 256, 0, stream>>>(Wq, wqkvt,          256, 256, 65536, 196608);
    twt_k<<<dim3(8, 8, NL), 256, 0, stream>>>(Wk, wqkvt + 65536,  256, 256, 65536, 196608);
    twt_k<<<dim3(8, 8, NL), 256, 0, stream>>>(Wv, wqkvt + 131072, 256, 256, 65536, 196608);
    twt_k<<<dim3(8, 8, NL), 256, 0, stream>>>(Wo, wot, 256, 256, 65536, 65536);
    twt_k<<<dim3(32, 8, NL), 256, 0, stream>>>(W1, w1t, 256, 1024, 262144, 262144);
    twt_k<<<dim3(8, 32, NL), 256, 0, stream>>>(W2, w2t, 1024, 256, 262144, 262144);
    pack_bias_k<<<(NL * 768 + 255) / 256, 256, 0, stream>>>(bq, bk, bv, bqkv);

    for (int l = 0; l < NL; ++l) {
        ln_k<<<MTOK / 4, 256, 0, stream>>>(x, ln1_g + l*256, ln1_b + l*256, nx);
        mm_k<128, 0><<<dim3(6, 112), 256, 0, stream>>>(
            nx, 256, wqkvt + (size_t)l*196608, bqkv + l*768, qkv, 768, 256);
        vt_k<<<dim3(14, 8, 32), 256, 0, stream>>>(qkv, vtg);
        attn_k<<<1792, 256, 0, stream>>>(qkv, vtg, mask, ob);
        mm_k<64, 2><<<dim3(4, 112), 256, 0, stream>>>(
            ob, 256, wot + (size_t)l*65536, bo + l*256, x, 256, 256);
        ln_k<<<MTOK / 4, 256, 0, stream>>>(x, ln2_g + l*256, ln2_b + l*256, nx);
        mm_k<128, 1><<<dim3(8, 112), 256, 0, stream>>>(
            nx, 256, w1t + (size_t)l*262144, bf1 + l*1024, hb, 1024, 256);
        mm_k<64, 2><<<dim3(4, 112), 256, 0, stream>>>(
            hb, 1024, w2t + (size_t)l*262144, bf2 + l*256, x, 256, 1024);
    }
}

// Round 4
// 1562.618 us; speedup vs baseline: 5.5172x; 1.0944x over previous
//
#include <hip/hip_runtime.h>

#define NL 12
#define DM 256
#define FFDIM 1024
#define BBATCH 32
#define LSEQ 448
#define MTOK (BBATCH*LSEQ)     // 14336
#define EPSF 1e-6f

typedef __attribute__((ext_vector_type(8))) short bf16x8;
typedef __attribute__((ext_vector_type(4))) float f32x4;
typedef unsigned short u16;
typedef unsigned int u32;

__device__ __forceinline__ u16 f2bf(float f) {
    union { float f; u32 u; } v; v.f = f;
    u32 r = v.u + 0x7fffu + ((v.u >> 16) & 1u);
    return (u16)(r >> 16);
}
__device__ __forceinline__ float gelu_exact(float x) {
    return 0.5f * x * (1.0f + erff(x * 0.70710678118654752f));
}
__device__ __forceinline__ void gload16(const u16* g, u16* l) {
    __builtin_amdgcn_global_load_lds(
        (const __attribute__((address_space(1))) u32*)g,
        (__attribute__((address_space(3))) u32*)l, 16, 0, 0);
}

// ---------------------------------------------------------------------------
__global__ __launch_bounds__(256) void add_pos_k(
    const float* __restrict__ x, const float* __restrict__ pe, float* __restrict__ out)
{
    int i = blockIdx.x * 256 + threadIdx.x;
    float4 xv = ((const float4*)x)[i];
    float4 pv = ((const float4*)pe)[i % (LSEQ * DM / 4)];
    float4 r;
    r.x = xv.x + pv.x; r.y = xv.y + pv.y; r.z = xv.z + pv.z; r.w = xv.w + pv.w;
    ((float4*)out)[i] = r;
}

// ---------------------------------------------------------------------------
__global__ __launch_bounds__(256) void ln_k(
    const float* __restrict__ x, const float* __restrict__ g,
    const float* __restrict__ b, u16* __restrict__ out)
{
    const int w = threadIdx.x >> 6, lane = threadIdx.x & 63;
    const int row = blockIdx.x * 4 + w;
    float4 v = ((const float4*)(x + (size_t)row * DM))[lane];
    float s = v.x + v.y + v.z + v.w;
#pragma unroll
    for (int off = 32; off; off >>= 1) s += __shfl_xor(s, off);
    float mu = s * (1.0f / 256.0f);
    float d0 = v.x - mu, d1 = v.y - mu, d2 = v.z - mu, d3 = v.w - mu;
    float sq = d0*d0 + d1*d1 + d2*d2 + d3*d3;
#pragma unroll
    for (int off = 32; off; off >>= 1) sq += __shfl_xor(sq, off);
    float rs = rsqrtf(sq * (1.0f / 256.0f) + EPSF);
    float4 gv = ((const float4*)g)[lane];
    float4 bv = ((const float4*)b)[lane];
    ushort4 o;
    o.x = f2bf(d0 * rs * gv.x + bv.x);
    o.y = f2bf(d1 * rs * gv.y + bv.y);
    o.z = f2bf(d2 * rs * gv.z + bv.z);
    o.w = f2bf(d3 * rs * gv.w + bv.w);
    *(ushort4*)(out + (size_t)row * DM + lane * 4) = o;
}

// ---------------------------------------------------------------------------
// Weight transpose + cvt: fp32 [layer][K][N] -> bf16 [layer][N][K]
__global__ __launch_bounds__(256) void twt_k(
    const float* __restrict__ in, u16* __restrict__ out,
    int K, int N, int in_lstride, int out_lstride)
{
    __shared__ float tl[32][33];
    const int l = blockIdx.z;
    const int n0 = blockIdx.x * 32, k0 = blockIdx.y * 32;
    const int tx = threadIdx.x & 31, ty = threadIdx.x >> 5;
    const float* src = in + (size_t)l * in_lstride;
#pragma unroll
    for (int i = 0; i < 4; ++i)
        tl[ty + 8*i][tx] = src[(size_t)(k0 + ty + 8*i) * N + n0 + tx];
    __syncthreads();
    u16* dst = out + (size_t)l * out_lstride;
#pragma unroll
    for (int i = 0; i < 4; ++i)
        dst[(size_t)(n0 + ty + 8*i) * K + k0 + tx] = f2bf(tl[tx][ty + 8*i]);
}

__global__ __launch_bounds__(256) void pack_bias_k(
    const float* __restrict__ bq, const float* __restrict__ bk,
    const float* __restrict__ bv, float* __restrict__ bqkv)
{
    int i = blockIdx.x * 256 + threadIdx.x;
    if (i >= NL * 768) return;
    int l = i / 768, c = i % 768;
    float v = (c < 256) ? bq[l*256 + c] : (c < 512) ? bk[l*256 + c - 256] : bv[l*256 + c - 512];
    bqkv[i] = v;
}

// ---------------------------------------------------------------------------
// V transpose per layer: qkv cols [512,768) -> vtg [b][h][d=32][key=448]
__global__ __launch_bounds__(256) void vt_k(
    const u16* __restrict__ qkv, u16* __restrict__ vtg)
{
    __shared__ u16 tl[32][33];
    const int kt = blockIdx.x, h = blockIdx.y, b = blockIdx.z;
    const int tx = threadIdx.x & 31, ty = threadIdx.x >> 5;
#pragma unroll
    for (int i = 0; i < 4; ++i)
        tl[ty + 8*i][tx] = qkv[(size_t)(b*LSEQ + kt*32 + ty + 8*i) * 768 + 512 + h*32 + tx];
    __syncthreads();
#pragma unroll
    for (int i = 0; i < 4; ++i)
        vtg[((size_t)(b*8 + h)*32 + ty + 8*i) * 448 + kt*32 + tx] = tl[tx][ty + 8*i];
}

// ---------------------------------------------------------------------------
// bf16 MFMA GEMM: C = A[M,K] @ Bt[N,K]^T + bias. BM=128, BK=64 (2x32 panels).
// Grid: (Mblocks=112, Nblocks) -> blockIdx.x = M (112%8==0: A-rows pin to XCD).
// EPI: 0 = bf16 store, 1 = gelu->bf16 store, 2 = fp32 residual +=
template<int BN, int EPI>
__global__ __launch_bounds__(256, 2) void mm_k(
    const u16* __restrict__ A, int lda, const u16* __restrict__ Bt,
    const float* __restrict__ bias, void* __restrict__ C, int ldc, int K)
{
    __shared__ u16 As[2 * 128 * 32];
    __shared__ u16 Bs[2 * BN * 32];
    constexpr int MT = (BN == 128) ? 4 : 2;
    constexpr int BPANEL = BN * 32;
    const int tid = threadIdx.x;
    const int by = blockIdx.x, bx = blockIdx.y;   // by = M-block, bx = N-block
    const int w = tid >> 6, lane = tid & 63;
    const int lm = lane & 15, lk = lane >> 4;
    const int wm = (BN == 128) ? (w >> 1) : w;
    const int wn = (BN == 128) ? (w & 1) : 0;
    const int m0 = wm * MT * 16;
    const int n0 = wn * 64;
    const int lrow = lane >> 2, lcol = (lane & 3) * 8;

    const u16* Ab = A + (size_t)(by * 128) * lda;
    const u16* Bb = Bt + (size_t)(bx * BN) * K;

    f32x4 zz = {0.f, 0.f, 0.f, 0.f};
    f32x4 acc[MT][4];
#pragma unroll
    for (int i = 0; i < MT; ++i)
#pragma unroll
        for (int j = 0; j < 4; ++j) acc[i][j] = zz;

    for (int k0 = 0; k0 < K; k0 += 64) {
        __syncthreads();
#pragma unroll
        for (int p = 0; p < 2; ++p) {
#pragma unroll
            for (int i = 0; i < 2; ++i) {
                int seg = w * 2 + i;
                gload16(Ab + (size_t)(seg * 16 + lrow) * lda + k0 + p * 32 + lcol,
                        &As[p * 4096 + seg * 512]);
            }
            if constexpr (BN == 128) {
#pragma unroll
                for (int i = 0; i < 2; ++i) {
                    int seg = w * 2 + i;
                    gload16(Bb + (size_t)(seg * 16 + lrow) * K + k0 + p * 32 + lcol,
                            &Bs[p * BPANEL + seg * 512]);
                }
            } else {
                gload16(Bb + (size_t)(w * 16 + lrow) * K + k0 + p * 32 + lcol,
                        &Bs[p * BPANEL + w * 512]);
            }
        }
        __syncthreads();

#pragma unroll
        for (int p = 0; p < 2; ++p) {
            bf16x8 af[MT], bfr[4];
#pragma unroll
            for (int mt = 0; mt < MT; ++mt)
                af[mt] = *(const bf16x8*)&As[p * 4096 + (m0 + mt*16 + lm)*32 + lk*8];
#pragma unroll
            for (int nt = 0; nt < 4; ++nt)
                bfr[nt] = *(const bf16x8*)&Bs[p * BPANEL + (n0 + nt*16 + lm)*32 + lk*8];
#pragma unroll
            for (int mt = 0; mt < MT; ++mt)
#pragma unroll
                for (int nt = 0; nt < 4; ++nt)
                    acc[mt][nt] = __builtin_amdgcn_mfma_f32_16x16x32_bf16(af[mt], bfr[nt], acc[mt][nt], 0, 0, 0);
        }
    }

    float bv[4];
#pragma unroll
    for (int nt = 0; nt < 4; ++nt) bv[nt] = bias[bx*BN + n0 + nt*16 + lm];
#pragma unroll
    for (int mt = 0; mt < MT; ++mt) {
#pragma unroll
        for (int r = 0; r < 4; ++r) {
            int grow = by*128 + m0 + mt*16 + lk*4 + r;
#pragma unroll
            for (int nt = 0; nt < 4; ++nt) {
                int gcol = bx*BN + n0 + nt*16 + lm;
                float vv = acc[mt][nt][r] + bv[nt];
                if constexpr (EPI == 0) {
                    ((u16*)C)[(size_t)grow * ldc + gcol] = f2bf(vv);
                } else if constexpr (EPI == 1) {
                    ((u16*)C)[(size_t)grow * ldc + gcol] = f2bf(gelu_exact(vv));
                } else {
                    float* p = (float*)C + (size_t)grow * ldc + gcol;
                    *p += vv;
                }
            }
        }
    }
}

// ---------------------------------------------------------------------------
// MFMA attention. Grid 1792: bid = sg*256 + bh so bid%8 == bh%8 — all 7
// strip-blocks of one (b,h) land on the same XCD (K/V reuse served by L2).
__global__ __launch_bounds__(256, 2) void attn_k(
    const u16* __restrict__ qkv, const u16* __restrict__ vtg,
    const unsigned char* __restrict__ mask, u16* __restrict__ ob)
{
    __shared__ u16 Klds[448 * 32];
    __shared__ u16 Plds[4][16 * 68];
    const int tid = threadIdx.x, w = tid >> 6, lane = tid & 63;
    const int lm = lane & 15, lk = lane >> 4;
    const int bid = blockIdx.x;
    const int bh = bid & 255, sg = bid >> 8;
    const int b = bh >> 3, h = bh & 7;
    const size_t rowbase = (size_t)b * LSEQ;

#pragma unroll
    for (int i = 0; i < 7; ++i) {
        int seg = w * 7 + i;
        gload16(qkv + (rowbase + seg * 16 + (lane >> 2)) * 768 + 256 + h * 32 + (lane & 3) * 8,
                &Klds[seg * 512]);
    }
    unsigned mbits = 0;
#pragma unroll
    for (int t = 0; t < 28; ++t)
        mbits |= (mask[b * LSEQ + t * 16 + lm] ? 1u : 0u) << t;
    __syncthreads();

    const u16* Vb = vtg + (size_t)bh * 32 * 448;
    const float scale = 0.17677669529663687f;
    f32x4 zz = {0.f, 0.f, 0.f, 0.f};

    const int q0 = (sg * 4 + w) * 16;
    bf16x8 qf = *(const bf16x8*)(qkv + (rowbase + q0 + lm) * 768 + h * 32 + lk * 8);
    f32x4 sc[28];
#pragma unroll
    for (int t = 0; t < 28; ++t) {
        bf16x8 kf = *(const bf16x8*)&Klds[(t*16 + lm)*32 + lk*8];
        sc[t] = __builtin_amdgcn_mfma_f32_16x16x32_bf16(qf, kf, zz, 0, 0, 0);
    }
    float mx[4] = {-1e30f, -1e30f, -1e30f, -1e30f};
#pragma unroll
    for (int t = 0; t < 28; ++t) {
        bool m = (mbits >> t) & 1;
#pragma unroll
        for (int r = 0; r < 4; ++r) {
            float v = m ? -10000.0f : sc[t][r] * scale;
            sc[t][r] = v;
            mx[r] = fmaxf(mx[r], v);
        }
    }
#pragma unroll
    for (int off = 1; off < 16; off <<= 1)
#pragma unroll
        for (int r = 0; r < 4; ++r) mx[r] = fmaxf(mx[r], __shfl_xor(mx[r], off));
    float sum[4] = {0.f, 0.f, 0.f, 0.f};
#pragma unroll
    for (int t = 0; t < 28; ++t)
#pragma unroll
        for (int r = 0; r < 4; ++r) {
            float e = __expf(sc[t][r] - mx[r]);
            sc[t][r] = e;
            sum[r] += e;
        }
#pragma unroll
    for (int off = 1; off < 16; off <<= 1)
#pragma unroll
        for (int r = 0; r < 4; ++r) sum[r] += __shfl_xor(sum[r], off);
    float inv[4];
#pragma unroll
    for (int r = 0; r < 4; ++r) inv[r] = 1.0f / sum[r];

    f32x4 oacc[2] = {zz, zz};
    u16* P = &Plds[w][0];
#pragma unroll
    for (int cc = 0; cc < 7; ++cc) {
#pragma unroll
        for (int tt = 0; tt < 4; ++tt) {
            int t = cc*4 + tt;
#pragma unroll
            for (int r = 0; r < 4; ++r)
                P[(lk*4 + r)*68 + tt*16 + lm] = f2bf(sc[t][r]);
        }
        bf16x8 pa0 = *(const bf16x8*)&P[lm*68 + lk*8];
        bf16x8 pa1 = *(const bf16x8*)&P[lm*68 + 32 + lk*8];
#pragma unroll
        for (int dt = 0; dt < 2; ++dt) {
            bf16x8 vb0 = *(const bf16x8*)(Vb + (size_t)(dt*16 + lm)*448 + cc*64 + lk*8);
            bf16x8 vb1 = *(const bf16x8*)(Vb + (size_t)(dt*16 + lm)*448 + cc*64 + 32 + lk*8);
            oacc[dt] = __builtin_amdgcn_mfma_f32_16x16x32_bf16(pa0, vb0, oacc[dt], 0, 0, 0);
            oacc[dt] = __builtin_amdgcn_mfma_f32_16x16x32_bf16(pa1, vb1, oacc[dt], 0, 0, 0);
        }
    }
#pragma unroll
    for (int dt = 0; dt < 2; ++dt)
#pragma unroll
        for (int r = 0; r < 4; ++r)
            ob[(rowbase + q0 + lk*4 + r)*256 + h*32 + dt*16 + lm] = f2bf(oacc[dt][r] * inv[r]);
}

// ---------------------------------------------------------------------------
extern "C" void kernel_launch(void* const* d_in, const int* in_sizes, int n_in,
                              void* d_out, int out_size, void* d_ws, size_t ws_size,
                              hipStream_t stream)
{
    const float* x_in = (const float*)d_in[0];
    const unsigned char* mask = (const unsigned char*)d_in[1];
    const float* pe   = (const float*)d_in[2];
    const float* Wq = (const float*)d_in[3];
    const float* bq = (const float*)d_in[4];
    const float* Wk = (const float*)d_in[5];
    const float* bk = (const float*)d_in[6];
    const float* Wv = (const float*)d_in[7];
    const float* bv = (const float*)d_in[8];
    const float* Wo = (const float*)d_in[9];
    const float* bo = (const float*)d_in[10];
    const float* W1 = (const float*)d_in[11];
    const float* bf1 = (const float*)d_in[12];
    const float* W2 = (const float*)d_in[13];
    const float* bf2 = (const float*)d_in[14];
    const float* ln1_g = (const float*)d_in[15];
    const float* ln1_b = (const float*)d_in[16];
    const float* ln2_g = (const float*)d_in[17];
    const float* ln2_b = (const float*)d_in[18];

    float* x = (float*)d_out;                 // fp32 residual stream [M,256]
    u16* ws = (u16*)d_ws;
    u16* nx   = ws;                           //  [M,256] bf16
    u16* qkv  = nx + 3670016;                 //  [M,768] bf16
    u16* ob   = qkv + 11010048;               //  [M,256] bf16
    u16* vtg  = ob + 3670016;                 //  [b,h,32,448] bf16
    u16* hb   = qkv;                          //  [M,1024] bf16 (aliases qkv)
    u16* wqkvt = vtg + 3670016;               //  [12][768][256]
    u16* wot  = wqkvt + 2359296;              //  [12][256][256]
    u16* w1t  = wot + 786432;                 //  [12][1024][256]
    u16* w2t  = w1t + 3145728;                //  [12][256][1024]
    float* bqkv = (float*)(w2t + 3145728);    //  [12][768]

    add_pos_k<<<MTOK * DM / 1024, 256, 0, stream>>>(x_in, pe, x);

    twt_k<<<dim3(8, 8, NL), 256, 0, stream>>>(Wq, wqkvt,          256, 256, 65536, 196608);
    twt_k<<<dim3(8, 8, NL), 256, 0, stream>>>(Wk, wqkvt + 65536,  256, 256, 65536, 196608);
    twt_k<<<dim3(8, 8, NL), 256, 0, stream>>>(Wv, wqkvt + 131072, 256, 256, 65536, 196608);
    twt_k<<<dim3(8, 8, NL), 256, 0, stream>>>(Wo, wot, 256, 256, 65536, 65536);
    twt_k<<<dim3(32, 8, NL), 256, 0, stream>>>(W1, w1t, 256, 1024, 262144, 262144);
    twt_k<<<dim3(8, 32, NL), 256, 0, stream>>>(W2, w2t, 1024, 256, 262144, 262144);
    pack_bias_k<<<(NL * 768 + 255) / 256, 256, 0, stream>>>(bq, bk, bv, bqkv);

    for (int l = 0; l < NL; ++l) {
        ln_k<<<MTOK / 4, 256, 0, stream>>>(x, ln1_g + l*256, ln1_b + l*256, nx);
        mm_k<128, 0><<<dim3(112, 6), 256, 0, stream>>>(
            nx, 256, wqkvt + (size_t)l*196608, bqkv + l*768, qkv, 768, 256);
        vt_k<<<dim3(14, 8, 32), 256, 0, stream>>>(qkv, vtg);
        attn_k<<<1792, 256, 0, stream>>>(qkv, vtg, mask, ob);
        mm_k<64, 2><<<dim3(112, 4), 256, 0, stream>>>(
            ob, 256, wot + (size_t)l*65536, bo + l*256, x, 256, 256);
        ln_k<<<MTOK / 4, 256, 0, stream>>>(x, ln2_g + l*256, ln2_b + l*256, nx);
        mm_k<128, 1><<<dim3(112, 8), 256, 0, stream>>>(
            nx, 256, w1t + (size_t)l*262144, bf1 + l*1024, hb, 1024, 256);
        mm_k<64, 2><<<dim3(112, 4), 256, 0, stream>>>(
            hb, 1024, w2t + (size_t)l*262144, bf2 + l*256, x, 256, 1024);
    }
}

// Round 5
// 1456.073 us; speedup vs baseline: 5.9209x; 1.0732x over previous
//
#include <hip/hip_runtime.h>

#define NL 12
#define DM 256
#define FFDIM 1024
#define BBATCH 32
#define LSEQ 448
#define MTOK (BBATCH*LSEQ)     // 14336
#define EPSF 1e-6f
#define QSCALE 0.17677669529663687f

typedef __attribute__((ext_vector_type(8))) short bf16x8;
typedef __attribute__((ext_vector_type(4))) float f32x4;
typedef unsigned short u16;
typedef unsigned int u32;

__device__ __forceinline__ u16 f2bf(float f) {
    union { float f; u32 u; } v; v.f = f;
    u32 r = v.u + 0x7fffu + ((v.u >> 16) & 1u);
    return (u16)(r >> 16);
}
__device__ __forceinline__ float gelu_exact(float x) {
    return 0.5f * x * (1.0f + erff(x * 0.70710678118654752f));
}
__device__ __forceinline__ void gload16(const u16* g, u16* l) {
    __builtin_amdgcn_global_load_lds(
        (const __attribute__((address_space(1))) u32*)g,
        (__attribute__((address_space(3))) u32*)l, 16, 0, 0);
}

// ---------------------------------------------------------------------------
__global__ __launch_bounds__(256) void add_pos_k(
    const float* __restrict__ x, const float* __restrict__ pe, float* __restrict__ out)
{
    int i = blockIdx.x * 256 + threadIdx.x;
    float4 xv = ((const float4*)x)[i];
    float4 pv = ((const float4*)pe)[i % (LSEQ * DM / 4)];
    float4 r;
    r.x = xv.x + pv.x; r.y = xv.y + pv.y; r.z = xv.z + pv.z; r.w = xv.w + pv.w;
    ((float4*)out)[i] = r;
}

// ---------------------------------------------------------------------------
__global__ __launch_bounds__(256) void ln_k(
    const float* __restrict__ x, const float* __restrict__ g,
    const float* __restrict__ b, u16* __restrict__ out)
{
    const int w = threadIdx.x >> 6, lane = threadIdx.x & 63;
    const int row = blockIdx.x * 4 + w;
    float4 v = ((const float4*)(x + (size_t)row * DM))[lane];
    float s = v.x + v.y + v.z + v.w;
#pragma unroll
    for (int off = 32; off; off >>= 1) s += __shfl_xor(s, off);
    float mu = s * (1.0f / 256.0f);
    float d0 = v.x - mu, d1 = v.y - mu, d2 = v.z - mu, d3 = v.w - mu;
    float sq = d0*d0 + d1*d1 + d2*d2 + d3*d3;
#pragma unroll
    for (int off = 32; off; off >>= 1) sq += __shfl_xor(sq, off);
    float rs = rsqrtf(sq * (1.0f / 256.0f) + EPSF);
    float4 gv = ((const float4*)g)[lane];
    float4 bv = ((const float4*)b)[lane];
    ushort4 o;
    o.x = f2bf(d0 * rs * gv.x + bv.x);
    o.y = f2bf(d1 * rs * gv.y + bv.y);
    o.z = f2bf(d2 * rs * gv.z + bv.z);
    o.w = f2bf(d3 * rs * gv.w + bv.w);
    *(ushort4*)(out + (size_t)row * DM + lane * 4) = o;
}

// ---------------------------------------------------------------------------
// Weight transpose + cvt: fp32 [layer][K][N] -> bf16 [layer][N][K]
__global__ __launch_bounds__(256) void twt_k(
    const float* __restrict__ in, u16* __restrict__ out,
    int K, int N, int in_lstride, int out_lstride)
{
    __shared__ float tl[32][33];
    const int l = blockIdx.z;
    const int n0 = blockIdx.x * 32, k0 = blockIdx.y * 32;
    const int tx = threadIdx.x & 31, ty = threadIdx.x >> 5;
    const float* src = in + (size_t)l * in_lstride;
#pragma unroll
    for (int i = 0; i < 4; ++i)
        tl[ty + 8*i][tx] = src[(size_t)(k0 + ty + 8*i) * N + n0 + tx];
    __syncthreads();
    u16* dst = out + (size_t)l * out_lstride;
#pragma unroll
    for (int i = 0; i < 4; ++i)
        dst[(size_t)(n0 + ty + 8*i) * K + k0 + tx] = f2bf(tl[tx][ty + 8*i]);
}

__global__ __launch_bounds__(256) void pack_bias_k(
    const float* __restrict__ bq, const float* __restrict__ bk,
    const float* __restrict__ bv, float* __restrict__ bqkv)
{
    int i = blockIdx.x * 256 + threadIdx.x;
    if (i >= NL * 768) return;
    int l = i / 768, c = i % 768;
    float v = (c < 256) ? bq[l*256 + c] : (c < 512) ? bk[l*256 + c - 256] : bv[l*256 + c - 512];
    bqkv[i] = v;
}

// ---------------------------------------------------------------------------
// V transpose per layer: qkv cols [512,768) -> vtg [b][h][d=32][key=448]
__global__ __launch_bounds__(256) void vt_k(
    const u16* __restrict__ qkv, u16* __restrict__ vtg)
{
    __shared__ u16 tl[32][33];
    const int kt = blockIdx.x, h = blockIdx.y, b = blockIdx.z;
    const int tx = threadIdx.x & 31, ty = threadIdx.x >> 5;
#pragma unroll
    for (int i = 0; i < 4; ++i)
        tl[ty + 8*i][tx] = qkv[(size_t)(b*LSEQ + kt*32 + ty + 8*i) * 768 + 512 + h*32 + tx];
    __syncthreads();
#pragma unroll
    for (int i = 0; i < 4; ++i)
        vtg[((size_t)(b*8 + h)*32 + ty + 8*i) * 448 + kt*32 + tx] = tl[tx][ty + 8*i];
}

// ---------------------------------------------------------------------------
// bf16 MFMA GEMM: C = A[M,K] @ Bt[N,K]^T + bias. BK=64 (2x32 panels).
// Configs: BM=BN=128 (4 waves, 2x2 wave grid) or BM=BN=64 (wave = 16-row strip).
// Grid (Mblocks, Nblocks); Mblocks%8==0 pins same-A blocks to one XCD.
// EPI: 0 bf16 store, 1 gelu->bf16, 2 fp32 residual +=, 3 bf16 store w/ qscale on cols<256
template<int BM, int BN, int EPI>
__global__ __launch_bounds__(256, (BM == 64) ? 4 : 3) void mm_k(
    const u16* __restrict__ A, int lda, const u16* __restrict__ Bt,
    const float* __restrict__ bias, void* __restrict__ C, int ldc, int K)
{
    __shared__ u16 As[2 * BM * 32];
    __shared__ u16 Bs[2 * BN * 32];
    constexpr int MT = (BM == 128) ? 4 : 1;
    constexpr int APANEL = BM * 32;
    constexpr int BPANEL = BN * 32;
    const int tid = threadIdx.x;
    const int by = blockIdx.x, bx = blockIdx.y;   // by = M-block, bx = N-block
    const int w = tid >> 6, lane = tid & 63;
    const int lm = lane & 15, lk = lane >> 4;
    const int m0 = (BM == 128) ? ((w >> 1) * 64) : (w * 16);
    const int n0 = (BM == 128) ? ((w & 1) * 64) : 0;
    const int lrow = lane >> 2, lcol = (lane & 3) * 8;

    const u16* Ab = A + (size_t)(by * BM) * lda;
    const u16* Bb = Bt + (size_t)(bx * BN) * K;

    f32x4 zz = {0.f, 0.f, 0.f, 0.f};
    f32x4 acc[MT][4];
#pragma unroll
    for (int i = 0; i < MT; ++i)
#pragma unroll
        for (int j = 0; j < 4; ++j) acc[i][j] = zz;

    for (int k0 = 0; k0 < K; k0 += 64) {
        __syncthreads();
#pragma unroll
        for (int p = 0; p < 2; ++p) {
            if constexpr (BM == 128) {
#pragma unroll
                for (int i = 0; i < 2; ++i) {
                    int seg = w * 2 + i;
                    gload16(Ab + (size_t)(seg * 16 + lrow) * lda + k0 + p * 32 + lcol,
                            &As[p * APANEL + seg * 512]);
                    gload16(Bb + (size_t)(seg * 16 + lrow) * K + k0 + p * 32 + lcol,
                            &Bs[p * BPANEL + seg * 512]);
                }
            } else {
                gload16(Ab + (size_t)(w * 16 + lrow) * lda + k0 + p * 32 + lcol,
                        &As[p * APANEL + w * 512]);
                gload16(Bb + (size_t)(w * 16 + lrow) * K + k0 + p * 32 + lcol,
                        &Bs[p * BPANEL + w * 512]);
            }
        }
        __syncthreads();

#pragma unroll
        for (int p = 0; p < 2; ++p) {
            bf16x8 af[MT], bfr[4];
#pragma unroll
            for (int mt = 0; mt < MT; ++mt)
                af[mt] = *(const bf16x8*)&As[p * APANEL + (m0 + mt*16 + lm)*32 + lk*8];
#pragma unroll
            for (int nt = 0; nt < 4; ++nt)
                bfr[nt] = *(const bf16x8*)&Bs[p * BPANEL + (n0 + nt*16 + lm)*32 + lk*8];
#pragma unroll
            for (int mt = 0; mt < MT; ++mt)
#pragma unroll
                for (int nt = 0; nt < 4; ++nt)
                    acc[mt][nt] = __builtin_amdgcn_mfma_f32_16x16x32_bf16(af[mt], bfr[nt], acc[mt][nt], 0, 0, 0);
        }
    }

    float bv[4];
#pragma unroll
    for (int nt = 0; nt < 4; ++nt) bv[nt] = bias[bx*BN + n0 + nt*16 + lm];
#pragma unroll
    for (int mt = 0; mt < MT; ++mt) {
#pragma unroll
        for (int r = 0; r < 4; ++r) {
            int grow = by*BM + m0 + mt*16 + lk*4 + r;
#pragma unroll
            for (int nt = 0; nt < 4; ++nt) {
                int gcol = bx*BN + n0 + nt*16 + lm;
                float vv = acc[mt][nt][r] + bv[nt];
                if constexpr (EPI == 0) {
                    ((u16*)C)[(size_t)grow * ldc + gcol] = f2bf(vv);
                } else if constexpr (EPI == 1) {
                    ((u16*)C)[(size_t)grow * ldc + gcol] = f2bf(gelu_exact(vv));
                } else if constexpr (EPI == 3) {
                    float qs = (gcol < 256) ? QSCALE : 1.0f;
                    ((u16*)C)[(size_t)grow * ldc + gcol] = f2bf(vv * qs);
                } else {
                    float* p = (float*)C + (size_t)grow * ldc + gcol;
                    *p += vv;
                }
            }
        }
    }
}

// ---------------------------------------------------------------------------
// MFMA attention, two-pass (low-register). Grid bid = sg*256 + bh (XCD pin).
// Pass 1: QK MFMAs, keep only row max. Pass 2: recompute QK per 64-key chunk,
// exp/sum/P->LDS/PV chunk-wise. Q is pre-scaled by 1/sqrt(dk) in QKV epilogue.
__global__ __launch_bounds__(256, 4) void attn_k(
    const u16* __restrict__ qkv, const u16* __restrict__ vtg,
    const unsigned char* __restrict__ mask, u16* __restrict__ ob)
{
    __shared__ u16 Klds[448 * 32];
    __shared__ u16 Plds[4][16 * 68];
    const int tid = threadIdx.x, w = tid >> 6, lane = tid & 63;
    const int lm = lane & 15, lk = lane >> 4;
    const int bid = blockIdx.x;
    const int bh = bid & 255, sg = bid >> 8;
    const int b = bh >> 3, h = bh & 7;
    const size_t rowbase = (size_t)b * LSEQ;

#pragma unroll
    for (int i = 0; i < 7; ++i) {
        int seg = w * 7 + i;
        gload16(qkv + (rowbase + seg * 16 + (lane >> 2)) * 768 + 256 + h * 32 + (lane & 3) * 8,
                &Klds[seg * 512]);
    }
    unsigned mbits = 0;
#pragma unroll
    for (int t = 0; t < 28; ++t)
        mbits |= (mask[b * LSEQ + t * 16 + lm] ? 1u : 0u) << t;
    __syncthreads();

    const u16* Vb = vtg + (size_t)bh * 32 * 448;
    f32x4 zz = {0.f, 0.f, 0.f, 0.f};

    const int q0 = (sg * 4 + w) * 16;
    bf16x8 qf = *(const bf16x8*)(qkv + (rowbase + q0 + lm) * 768 + h * 32 + lk * 8);

    // ---- pass 1: row max only ----
    float mx[4] = {-1e30f, -1e30f, -1e30f, -1e30f};
#pragma unroll
    for (int t = 0; t < 28; ++t) {
        bf16x8 kf = *(const bf16x8*)&Klds[(t*16 + lm)*32 + lk*8];
        f32x4 s = __builtin_amdgcn_mfma_f32_16x16x32_bf16(qf, kf, zz, 0, 0, 0);
        bool m = (mbits >> t) & 1;
#pragma unroll
        for (int r = 0; r < 4; ++r) {
            float v = m ? -10000.0f : s[r];
            mx[r] = fmaxf(mx[r], v);
        }
    }
#pragma unroll
    for (int off = 1; off < 16; off <<= 1)
#pragma unroll
        for (int r = 0; r < 4; ++r) mx[r] = fmaxf(mx[r], __shfl_xor(mx[r], off));

    // ---- pass 2: chunk-wise exp + PV ----
    f32x4 oacc[2] = {zz, zz};
    float sum[4] = {0.f, 0.f, 0.f, 0.f};
    u16* P = &Plds[w][0];
#pragma unroll
    for (int cc = 0; cc < 7; ++cc) {
#pragma unroll
        for (int tt = 0; tt < 4; ++tt) {
            int t = cc*4 + tt;
            bf16x8 kf = *(const bf16x8*)&Klds[(t*16 + lm)*32 + lk*8];
            f32x4 s = __builtin_amdgcn_mfma_f32_16x16x32_bf16(qf, kf, zz, 0, 0, 0);
            bool m = (mbits >> t) & 1;
#pragma unroll
            for (int r = 0; r < 4; ++r) {
                float v = m ? -10000.0f : s[r];
                float e = __expf(v - mx[r]);
                sum[r] += e;
                P[(lk*4 + r)*68 + tt*16 + lm] = f2bf(e);
            }
        }
        bf16x8 pa0 = *(const bf16x8*)&P[lm*68 + lk*8];
        bf16x8 pa1 = *(const bf16x8*)&P[lm*68 + 32 + lk*8];
#pragma unroll
        for (int dt = 0; dt < 2; ++dt) {
            bf16x8 vb0 = *(const bf16x8*)(Vb + (size_t)(dt*16 + lm)*448 + cc*64 + lk*8);
            bf16x8 vb1 = *(const bf16x8*)(Vb + (size_t)(dt*16 + lm)*448 + cc*64 + 32 + lk*8);
            oacc[dt] = __builtin_amdgcn_mfma_f32_16x16x32_bf16(pa0, vb0, oacc[dt], 0, 0, 0);
            oacc[dt] = __builtin_amdgcn_mfma_f32_16x16x32_bf16(pa1, vb1, oacc[dt], 0, 0, 0);
        }
    }
#pragma unroll
    for (int off = 1; off < 16; off <<= 1)
#pragma unroll
        for (int r = 0; r < 4; ++r) sum[r] += __shfl_xor(sum[r], off);
    float inv[4];
#pragma unroll
    for (int r = 0; r < 4; ++r) inv[r] = 1.0f / sum[r];

#pragma unroll
    for (int dt = 0; dt < 2; ++dt)
#pragma unroll
        for (int r = 0; r < 4; ++r)
            ob[(rowbase + q0 + lk*4 + r)*256 + h*32 + dt*16 + lm] = f2bf(oacc[dt][r] * inv[r]);
}

// ---------------------------------------------------------------------------
extern "C" void kernel_launch(void* const* d_in, const int* in_sizes, int n_in,
                              void* d_out, int out_size, void* d_ws, size_t ws_size,
                              hipStream_t stream)
{
    const float* x_in = (const float*)d_in[0];
    const unsigned char* mask = (const unsigned char*)d_in[1];
    const float* pe   = (const float*)d_in[2];
    const float* Wq = (const float*)d_in[3];
    const float* bq = (const float*)d_in[4];
    const float* Wk = (const float*)d_in[5];
    const float* bk = (const float*)d_in[6];
    const float* Wv = (const float*)d_in[7];
    const float* bv = (const float*)d_in[8];
    const float* Wo = (const float*)d_in[9];
    const float* bo = (const float*)d_in[10];
    const float* W1 = (const float*)d_in[11];
    const float* bf1 = (const float*)d_in[12];
    const float* W2 = (const float*)d_in[13];
    const float* bf2 = (const float*)d_in[14];
    const float* ln1_g = (const float*)d_in[15];
    const float* ln1_b = (const float*)d_in[16];
    const float* ln2_g = (const float*)d_in[17];
    const float* ln2_b = (const float*)d_in[18];

    float* x = (float*)d_out;                 // fp32 residual stream [M,256]
    u16* ws = (u16*)d_ws;
    u16* nx   = ws;                           //  [M,256] bf16
    u16* qkv  = nx + 3670016;                 //  [M,768] bf16 (Q pre-scaled)
    u16* ob   = qkv + 11010048;               //  [M,256] bf16
    u16* vtg  = ob + 3670016;                 //  [b,h,32,448] bf16
    u16* hb   = qkv;                          //  [M,1024] bf16 (aliases qkv)
    u16* wqkvt = vtg + 3670016;               //  [12][768][256]
    u16* wot  = wqkvt + 2359296;              //  [12][256][256]
    u16* w1t  = wot + 786432;                 //  [12][1024][256]
    u16* w2t  = w1t + 3145728;                //  [12][256][1024]
    float* bqkv = (float*)(w2t + 3145728);    //  [12][768]

    add_pos_k<<<MTOK * DM / 1024, 256, 0, stream>>>(x_in, pe, x);

    twt_k<<<dim3(8, 8, NL), 256, 0, stream>>>(Wq, wqkvt,          256, 256, 65536, 196608);
    twt_k<<<dim3(8, 8, NL), 256, 0, stream>>>(Wk, wqkvt + 65536,  256, 256, 65536, 196608);
    twt_k<<<dim3(8, 8, NL), 256, 0, stream>>>(Wv, wqkvt + 131072, 256, 256, 65536, 196608);
    twt_k<<<dim3(8, 8, NL), 256, 0, stream>>>(Wo, wot, 256, 256, 65536, 65536);
    twt_k<<<dim3(32, 8, NL), 256, 0, stream>>>(W1, w1t, 256, 1024, 262144, 262144);
    twt_k<<<dim3(8, 32, NL), 256, 0, stream>>>(W2, w2t, 1024, 256, 262144, 262144);
    pack_bias_k<<<(NL * 768 + 255) / 256, 256, 0, stream>>>(bq, bk, bv, bqkv);

    for (int l = 0; l < NL; ++l) {
        ln_k<<<MTOK / 4, 256, 0, stream>>>(x, ln1_g + l*256, ln1_b + l*256, nx);
        mm_k<128, 128, 3><<<dim3(112, 6), 256, 0, stream>>>(
            nx, 256, wqkvt + (size_t)l*196608, bqkv + l*768, qkv, 768, 256);
        vt_k<<<dim3(14, 8, 32), 256, 0, stream>>>(qkv, vtg);
        attn_k<<<1792, 256, 0, stream>>>(qkv, vtg, mask, ob);
        mm_k<64, 64, 2><<<dim3(224, 4), 256, 0, stream>>>(
            ob, 256, wot + (size_t)l*65536, bo + l*256, x, 256, 256);
        ln_k<<<MTOK / 4, 256, 0, stream>>>(x, ln2_g + l*256, ln2_b + l*256, nx);
        mm_k<128, 128, 1><<<dim3(112, 8), 256, 0, stream>>>(
            nx, 256, w1t + (size_t)l*262144, bf1 + l*1024, hb, 1024, 256);
        mm_k<64, 64, 2><<<dim3(224, 4), 256, 0, stream>>>(
            hb, 1024, w2t + (size_t)l*262144, bf2 + l*256, x, 256, 1024);
    }
}